// Round 8
// baseline (99.131 us; speedup 1.0000x reference)
//
#include <hip/hip_runtime.h>
#include <math.h>

constexpr int N_RAYS = 65536;
constexpr int NBLK   = 4096;   // 4096 blocks * 4 waves * 4 rays = 65536 rays
constexpr int NREP   = 4;      // DIAGNOSTIC: 4 identical full passes

// DPP helper: lanes with a valid source get dpp(src); invalid lanes keep `oldv`.
// (row = 16 lanes; row_shr:n = lane i reads lane i-n; row_shl:n = lane i reads i+n)
template<int CTRL>
__device__ __forceinline__ float dppf(float oldv, float x) {
    return __int_as_float(__builtin_amdgcn_update_dpp(
        __float_as_int(oldv), __float_as_int(x), CTRL, 0xF, 0xF, false));
}

__device__ __forceinline__ float row16_sum(float x) {
    x += dppf<0xB1>(0.0f, x);    // quad_perm(1,0,3,2)
    x += dppf<0x4E>(0.0f, x);    // quad_perm(2,3,0,1)
    x += dppf<0x141>(0.0f, x);   // row_half_mirror
    x += dppf<0x140>(0.0f, x);   // row_mirror
    return x;
}

// One wave = 4 rays (16 lanes/ray). Lane m owns samples 8m..8m+7 (one serial
// chain, single 16-lane scan, no carry). All loads issued up front.
// DIAGNOSTIC: NREP passes over permuted ray ids (XOR bijection) so the
// dispatch runs ~4x longer and surfaces in rocprof's top-5 with counters.
__global__ __launch_bounds__(256) void integrate_kernel(
    const float* __restrict__ raw,     // [N][128][4]
    const float* __restrict__ zvals,   // [N][128]
    const float* __restrict__ rays_d,  // [N][3]
    float* __restrict__ chs_map,       // [N][3]
    float* __restrict__ depth_map,     // [N]
    float* __restrict__ block_partials)
{
    const int lane = threadIdx.x & 63;
    const int warp = threadIdx.x >> 6;
    const int g    = lane >> 4;
    const int m    = lane & 15;

    const int gw   = blockIdx.x * 4 + warp;
    const int rayb = gw * 4 + g;

    float ent_final = 0.0f;

    #pragma unroll 1
    for (int rep = 0; rep < NREP; ++rep) {
        const int mask = (rep == 0) ? 0x15A5 :
                         (rep == 1) ? 0x2A5A :
                         (rep == 2) ? 0x3FC3 : 0;
        const int ray = rayb ^ mask;   // bijection on [0,65536)

        // ---- all global loads issued up front ----
        const float* rd = rays_d + (size_t)ray * 3;
        const float d0 = rd[0], d1 = rd[1], d2 = rd[2];

        const float* zr = zvals + (size_t)ray * 128;
        const float4 zA = *(const float4*)(zr + 8*m);
        const float4 zB = *(const float4*)(zr + 8*m + 4);

        const float4* rq = (const float4*)raw + (size_t)ray * 128;
        float4 q[8];
        #pragma unroll
        for (int j = 0; j < 8; ++j) q[j] = rq[8*m + j];

        const float norm = sqrtf(d0*d0 + d1*d1 + d2*d2);
        float z[8] = {zA.x, zA.y, zA.z, zA.w, zB.x, zB.y, zB.z, zB.w};
        const float zn = dppf<0x101>(z[0], z[0]);   // lane m+1's z[8m+8]; lane15 unused

        // dists
        float dd[8];
        #pragma unroll
        for (int j = 0; j < 7; ++j) dd[j] = (z[j+1] - z[j]) * norm;
        dd[7] = (m == 15) ? (1e10f * norm) : ((zn - z[7]) * norm);

        // alpha / t
        float alpha[8], tt[8];
        #pragma unroll
        for (int j = 0; j < 8; ++j) {
            const float sig = fmaxf(q[j].w, 0.0f);
            const float e   = __expf(-sig * dd[j]);
            alpha[j] = 1.0f - e;
            tt[j]    = e + 1e-10f;
        }

        // per-lane product, 16-lane inclusive scan, exclusive shift
        float p = tt[0];
        #pragma unroll
        for (int j = 1; j < 8; ++j) p *= tt[j];
        float sc = p;
        sc *= dppf<0x111>(1.0f, sc);   // row_shr:1
        sc *= dppf<0x112>(1.0f, sc);   // row_shr:2
        sc *= dppf<0x114>(1.0f, sc);   // row_shr:4
        sc *= dppf<0x118>(1.0f, sc);   // row_shr:8
        const float E = dppf<0x111>(1.0f, sc);   // exclusive (lane0 = 1)

        // weights + accumulation (serial chain over the lane's 8 samples)
        float c0=0.f, c1=0.f, c2=0.f, wsum=0.f, dnum=0.f, aa=0.f;
        float trj = E;
        #pragma unroll
        for (int j = 0; j < 8; ++j) {
            const float w = alpha[j] * trj;
            c0   += w * q[j].x;
            c1   += w * q[j].y;
            c2   += w * q[j].z;
            wsum += w;
            dnum += w * (6.0f - z[j]) * 0.25f;
            aa   += w * __logf(fmaxf(w, 1e-30f));
            trj  *= tt[j];
        }

        // 6-var allreduce within the 16-lane group (pure DPP)
        c0   = row16_sum(c0);
        c1   = row16_sum(c1);
        c2   = row16_sum(c2);
        wsum = row16_sum(wsum);
        dnum = row16_sum(dnum);
        aa   = row16_sum(aa);

        float ent = 0.0f;
        if (m == 0) {
            const float L = 1.0f - wsum + 1e-6f;
            const float psum = wsum + L;
            const float logpsum = __logf(psum);
            const float entL = (L > 0.0f) ? L * (__logf(L) - logpsum) : 0.0f;
            ent = -(aa - wsum * logpsum + entL) / psum;
        }

        if (mask == 0) {
            if (m == 0) {
                chs_map[(size_t)ray * 3 + 0] = c0;
                chs_map[(size_t)ray * 3 + 1] = c1;
                chs_map[(size_t)ray * 3 + 2] = c2;
                depth_map[ray] = dnum / (wsum + 1e-5f);
            }
            ent_final = ent;
        } else {
            // keep reps 0..2 fully live without writing (rule #17 sink)
            asm volatile("" :: "v"(ent), "v"(c0), "v"(c1), "v"(c2),
                              "v"(dnum), "v"(wsum));
        }
    }

    // entropy partials on lanes 0,16,32,48 -> lane 0
    ent_final += __shfl_xor(ent_final, 16);
    ent_final += __shfl_xor(ent_final, 32);

    __shared__ float sred[4];
    if (lane == 0) sred[warp] = ent_final;
    __syncthreads();
    if (threadIdx.x == 0)
        block_partials[blockIdx.x] = sred[0] + sred[1] + sred[2] + sred[3];
}

__global__ __launch_bounds__(1024) void reduce_kernel(
    const float* __restrict__ partials, float* __restrict__ out_scalar)
{
    float s = 0.0f;
    #pragma unroll
    for (int i = 0; i < NBLK / 1024; ++i)
        s += partials[threadIdx.x + i * 1024];
    #pragma unroll
    for (int d = 1; d < 64; d <<= 1) s += __shfl_xor(s, d);

    __shared__ float sr[16];
    const int lane = threadIdx.x & 63;
    const int warp = threadIdx.x >> 6;
    if (lane == 0) sr[warp] = s;
    __syncthreads();
    if (threadIdx.x == 0) {
        float tot = 0.0f;
        #pragma unroll
        for (int i = 0; i < 16; ++i) tot += sr[i];
        *out_scalar = tot;
    }
}

extern "C" void kernel_launch(void* const* d_in, const int* in_sizes, int n_in,
                              void* d_out, int out_size, void* d_ws, size_t ws_size,
                              hipStream_t stream) {
    const float* raw    = (const float*)d_in[0];
    const float* zvals  = (const float*)d_in[1];
    const float* rays_d = (const float*)d_in[2];

    float* out = (float*)d_out;
    float* chs_map   = out;                       // 65536*3
    float* depth_map = out + (size_t)N_RAYS * 3;  // 65536
    float* sparsity  = out + (size_t)N_RAYS * 4;  // 1

    float* partials = (float*)d_ws;               // NBLK floats

    integrate_kernel<<<NBLK, 256, 0, stream>>>(raw, zvals, rays_d,
                                               chs_map, depth_map, partials);
    reduce_kernel<<<1, 1024, 0, stream>>>(partials, sparsity);
}

// Round 9
// 31.813 us; speedup vs baseline: 3.1160x; 3.1160x over previous
//
#include <hip/hip_runtime.h>
#include <math.h>

constexpr int N_RAYS = 65536;
constexpr int NBLK   = 4096;   // 4096 blocks * 4 waves * 4 rays = 65536 rays

// DPP helper: lanes with a valid source get dpp(src); invalid lanes keep `oldv`.
// (row = 16 lanes; row_shr:n = lane i reads lane i-n; row_shl:n = lane i reads i+n)
template<int CTRL>
__device__ __forceinline__ float dppf(float oldv, float x) {
    return __int_as_float(__builtin_amdgcn_update_dpp(
        __float_as_int(oldv), __float_as_int(x), CTRL, 0xF, 0xF, false));
}

__device__ __forceinline__ float row16_sum(float x) {
    x += dppf<0xB1>(0.0f, x);    // quad_perm(1,0,3,2)
    x += dppf<0x4E>(0.0f, x);    // quad_perm(2,3,0,1)
    x += dppf<0x141>(0.0f, x);   // row_half_mirror
    x += dppf<0x140>(0.0f, x);   // row_mirror
    return x;
}

// One wave = 4 rays (16 lanes/ray = one DPP row). Lane m owns samples
// 8m..8m+7. ALL loads issued up front; __launch_bounds__(256,4) raises the
// VGPR ceiling to 128 so the whole batch stays in registers (10-deep MLP)
// instead of the 40-VGPR serialized rounds rocprof exposed in R8.
__global__ __launch_bounds__(256, 4) void integrate_kernel(
    const float* __restrict__ raw,     // [N][128][4]
    const float* __restrict__ zvals,   // [N][128]
    const float* __restrict__ rays_d,  // [N][3]
    float* __restrict__ chs_map,       // [N][3]
    float* __restrict__ depth_map,     // [N]
    float* __restrict__ block_partials)
{
    const int lane = threadIdx.x & 63;
    const int warp = threadIdx.x >> 6;
    const int g    = lane >> 4;
    const int m    = lane & 15;

    const int ray = (blockIdx.x * 4 + warp) * 4 + g;   // 0..65535

    // ---- all global loads issued up front, 32-bit offsets ----
    const float* rd = rays_d + ray * 3;
    const float d0 = rd[0], d1 = rd[1], d2 = rd[2];

    const float* zr = zvals + (ray << 7);
    const float4 zA = *(const float4*)(zr + 8 * m);
    const float4 zB = *(const float4*)(zr + 8 * m + 4);

    const float4* rq = (const float4*)raw + (ray << 7);
    float4 q[8];
    #pragma unroll
    for (int j = 0; j < 8; ++j) q[j] = rq[8 * m + j];

    const float norm = sqrtf(d0 * d0 + d1 * d1 + d2 * d2);
    float z[8] = {zA.x, zA.y, zA.z, zA.w, zB.x, zB.y, zB.z, zB.w};
    // lane m+1's z[8m+8] (lane 15 invalid -> keeps own z[0], unused there)
    const float zn = dppf<0x101>(z[0], z[0]);

    // per-sample survival t_j = exp(-relu(sigma)*dist) + 1e-10
    float tt[8];
    #pragma unroll
    for (int j = 0; j < 7; ++j)
        tt[j] = __expf(-fmaxf(q[j].w, 0.0f) * (z[j + 1] - z[j]) * norm) + 1e-10f;
    {
        const float dd7 = (m == 15) ? 1e10f : (zn - z[7]);
        tt[7] = __expf(-fmaxf(q[7].w, 0.0f) * dd7 * norm) + 1e-10f;
    }

    // lane-local product, 16-lane inclusive scan, exclusive shift
    float p = tt[0];
    #pragma unroll
    for (int j = 1; j < 8; ++j) p *= tt[j];
    float sc = p;
    sc *= dppf<0x111>(1.0f, sc);   // row_shr:1
    sc *= dppf<0x112>(1.0f, sc);   // row_shr:2
    sc *= dppf<0x114>(1.0f, sc);   // row_shr:4
    sc *= dppf<0x118>(1.0f, sc);   // row_shr:8
    float trj = dppf<0x111>(1.0f, sc);   // exclusive: row-lane0 -> 1

    // weights: w_j = trj_j - trj_{j+1}  (== alpha_j * trans_j - 1e-10*trj, err <= 1e-10)
    float c0 = 0.f, c1 = 0.f, c2 = 0.f, wsum = 0.f, wz = 0.f, aa2 = 0.f;
    #pragma unroll
    for (int j = 0; j < 8; ++j) {
        const float trjn = trj * tt[j];
        const float w    = trj - trjn;
        c0   += w * q[j].x;
        c1   += w * q[j].y;
        c2   += w * q[j].z;
        wsum += w;
        wz   += w * z[j];
        aa2  += w * __log2f(fmaxf(w, 1e-30f));   // log2 domain; scale later
        trj   = trjn;
    }

    // 6-var allreduce within the 16-lane row (pure DPP)
    c0   = row16_sum(c0);
    c1   = row16_sum(c1);
    c2   = row16_sum(c2);
    wsum = row16_sum(wsum);
    wz   = row16_sum(wz);
    aa2  = row16_sum(aa2);

    float ent = 0.0f;
    if (m == 0) {
        chs_map[ray * 3 + 0] = c0;
        chs_map[ray * 3 + 1] = c1;
        chs_map[ray * 3 + 2] = c2;
        const float dnum = (6.0f * wsum - wz) * 0.25f;
        depth_map[ray] = dnum / (wsum + 1e-5f);

        // sum p*log p = (A - W*log(psum) + L*(log L - log psum)) / psum
        const float aa = aa2 * 0.6931471806f;
        const float L = 1.0f - wsum + 1e-6f;
        const float psum = wsum + L;
        const float logpsum = __logf(psum);
        const float entL = (L > 0.0f) ? L * (__logf(L) - logpsum) : 0.0f;
        ent = -(aa - wsum * logpsum + entL) / psum;
    }
    // entropy partials on lanes 0,16,32,48 -> lane 0
    ent += __shfl_xor(ent, 16);
    ent += __shfl_xor(ent, 32);

    __shared__ float sred[4];
    if (lane == 0) sred[warp] = ent;
    __syncthreads();
    if (threadIdx.x == 0)
        block_partials[blockIdx.x] = sred[0] + sred[1] + sred[2] + sred[3];
}

__global__ __launch_bounds__(1024) void reduce_kernel(
    const float* __restrict__ partials, float* __restrict__ out_scalar)
{
    float s = 0.0f;
    #pragma unroll
    for (int i = 0; i < NBLK / 1024; ++i)
        s += partials[threadIdx.x + i * 1024];
    #pragma unroll
    for (int d = 1; d < 64; d <<= 1) s += __shfl_xor(s, d);

    __shared__ float sr[16];
    const int lane = threadIdx.x & 63;
    const int warp = threadIdx.x >> 6;
    if (lane == 0) sr[warp] = s;
    __syncthreads();
    if (threadIdx.x == 0) {
        float tot = 0.0f;
        #pragma unroll
        for (int i = 0; i < 16; ++i) tot += sr[i];
        *out_scalar = tot;
    }
}

extern "C" void kernel_launch(void* const* d_in, const int* in_sizes, int n_in,
                              void* d_out, int out_size, void* d_ws, size_t ws_size,
                              hipStream_t stream) {
    const float* raw    = (const float*)d_in[0];
    const float* zvals  = (const float*)d_in[1];
    const float* rays_d = (const float*)d_in[2];

    float* out = (float*)d_out;
    float* chs_map   = out;                       // 65536*3
    float* depth_map = out + (size_t)N_RAYS * 3;  // 65536
    float* sparsity  = out + (size_t)N_RAYS * 4;  // 1

    float* partials = (float*)d_ws;               // NBLK floats

    integrate_kernel<<<NBLK, 256, 0, stream>>>(raw, zvals, rays_d,
                                               chs_map, depth_map, partials);
    reduce_kernel<<<1, 1024, 0, stream>>>(partials, sparsity);
}